// Round 3
// baseline (2062.384 us; speedup 1.0000x reference)
//
#include <hip/hip_runtime.h>
#include <hip/hip_bf16.h>
#include <math.h>

// Problem constants
// x:(4,128,96,96) gate_w:(8,128,3,3) gate_bias:(8) expert_w:(8,128,128,3,3)
// expert_b:(8,128) shared_w:(128,128,3,3) shared_b:(128)  -> out:(4,128,96,96)

typedef __attribute__((ext_vector_type(8))) short short8;
typedef __attribute__((ext_vector_type(4))) float f32x4;

static __device__ __forceinline__ unsigned short f2bf(float f) {
    unsigned int u = __float_as_uint(f);
    unsigned int r = (u + 0x7FFFu + ((u >> 16) & 1u)) >> 16;
    return (unsigned short)r;
}

// ---------------------------------------------------------------------------
// Prep v2: LDS-transpose for coalesced read AND write.
// ew (8,128,128,3,3) + sw (128,128,3,3) -> bf16 pw[e(9)][tap(9)][co(128)][ci(128)]
// 144 blocks x 256 thr; each block handles 8 (e,co) pairs (1152 floats each).
// ---------------------------------------------------------------------------
__global__ __launch_bounds__(256) void prep_kernel(
    const float* __restrict__ ew, const float* __restrict__ sw,
    unsigned short* __restrict__ pw)
{
    __shared__ float buf[8][1152];
    const int t = threadIdx.x;
    const int P = blockIdx.x * 8;         // pair base; pair = e*128+co, e=8 -> shared
    for (int i = t; i < 9216; i += 256) {
        int pi   = i / 1152;
        int elem = i - pi * 1152;          // ci*9 + tap
        int pair = P + pi;
        int e  = pair >> 7;
        int co = pair & 127;
        float v = (e < 8) ? ew[(e * 128 + co) * 1152 + elem]
                          : sw[co * 1152 + elem];
        buf[pi][elem] = v;
    }
    __syncthreads();
    for (int o = t; o < 9216; o += 256) {
        int pi  = o / 1152;
        int r   = o - pi * 1152;
        int tap = r >> 7;
        int ci  = r & 127;
        int pair = P + pi;
        int e  = pair >> 7;
        int co = pair & 127;
        pw[((e * 9 + tap) * 128 + co) * 128 + ci] = f2bf(buf[pi][ci * 9 + tap]);
    }
}

// ---------------------------------------------------------------------------
// Gate v3: fp32 conv -> sigmoid -> top2 -> softmax -> dense score_full.
// Block = 256 thr: 8 ci-groups (16 ci) x 32 pixels (1 row x 32 cols).
// Grid = 1152 blocks => 4608 waves (~4.5 waves/SIMD).
// ---------------------------------------------------------------------------
__global__ __launch_bounds__(256) void gate_kernel(
    const float* __restrict__ x, const float* __restrict__ gw,
    const float* __restrict__ gb, float* __restrict__ scores)
{
    __shared__ float gws[9216];          // [ci][tap][e] — wave-uniform reads
    __shared__ float red[8][32][8];      // partials per ci-group

    const int t = threadIdx.x;
    for (int i = t; i < 9216; i += 256) {
        int ci  = i / 72;
        int r   = i - ci * 72;
        int tap = r >> 3;
        int e   = r & 7;
        gws[i] = gw[(e * 128 + ci) * 9 + tap];
    }
    __syncthreads();

    const int g  = t >> 5;               // ci-group (16 ci each)
    const int p  = t & 31;               // col within tile
    const int bx = blockIdx.x;
    const int wt = bx % 3;
    const int h  = (bx / 3) % 96;
    const int b  = bx / 288;
    const int w  = wt * 32 + p;

    int off[9]; float msk[9];
    #pragma unroll
    for (int kh = 0; kh < 3; kh++) {
        #pragma unroll
        for (int kw = 0; kw < 3; kw++) {
            int hh = h + kh - 1, ww = w + kw - 1;
            bool valid = (hh >= 0 && hh < 96 && ww >= 0 && ww < 96);
            int hc = min(max(hh, 0), 95), wc = min(max(ww, 0), 95);
            off[kh * 3 + kw] = hc * 96 + wc;
            msk[kh * 3 + kw] = valid ? 1.0f : 0.0f;
        }
    }

    const float* xb = x + (b * 128 + g * 16) * 9216;
    float acc[8] = {0.f,0.f,0.f,0.f,0.f,0.f,0.f,0.f};
    #pragma unroll 2
    for (int ci = 0; ci < 16; ci++) {
        const float* xc = xb + ci * 9216;
        const float* wr = &gws[(g * 16 + ci) * 72];
        float xv[9];
        #pragma unroll
        for (int tap = 0; tap < 9; tap++) xv[tap] = xc[off[tap]] * msk[tap];
        #pragma unroll
        for (int tap = 0; tap < 9; tap++) {
            #pragma unroll
            for (int e = 0; e < 8; e++) acc[e] += xv[tap] * wr[tap * 8 + e];
        }
    }

    #pragma unroll
    for (int e = 0; e < 8; e++) red[g][p][e] = acc[e];
    __syncthreads();

    if (t < 32) {
        float s[8], bs[8];
        #pragma unroll
        for (int e = 0; e < 8; e++) {
            float v = 0.f;
            #pragma unroll
            for (int gg = 0; gg < 8; gg++) v += red[gg][t][e];
            s[e]  = 1.0f / (1.0f + expf(-v));
            bs[e] = s[e] + gb[e];
        }
        int i1 = 0; float b1 = bs[0]; float w1 = s[0];
        #pragma unroll
        for (int e = 1; e < 8; e++)
            if (bs[e] > b1) { b1 = bs[e]; i1 = e; w1 = s[e]; }
        int i2 = -1; float b2 = -1e30f; float w2 = 0.f;
        #pragma unroll
        for (int e = 0; e < 8; e++)
            if (e != i1 && bs[e] > b2) { b2 = bs[e]; i2 = e; w2 = s[e]; }

        float mx = fmaxf(w1, w2);
        float e1 = expf(w1 - mx), e2 = expf(w2 - mx);
        float inv = 1.0f / (e1 + e2);
        float p1 = e1 * inv, p2 = e2 * inv;   // ROUTE_SCALE = 1

        int base = b * 8 * 9216 + h * 96 + wt * 32 + t;
        #pragma unroll
        for (int e = 0; e < 8; e++) {
            float v = (e == i1) ? p1 : ((e == i2) ? p2 : 0.0f);
            scores[base + e * 9216] = v;
        }
    }
}

// ---------------------------------------------------------------------------
// Main v2: tap-outer / expert-inner. B-frags in registers (reused 9 experts),
// A-frags direct global->VGPR (L2-resident), scale folded per (e,tap) partial.
// Block tile: 128 Cout x 64 pixels (2 rows x 32 cols). 4 waves, each 32 co.
// ---------------------------------------------------------------------------
__global__ __launch_bounds__(256, 2) void moe_main_kernel(
    const float* __restrict__ x, const unsigned short* __restrict__ pw,
    const float* __restrict__ scores, const float* __restrict__ eb,
    const float* __restrict__ sb, float* __restrict__ out)
{
    __shared__ unsigned short xs[4 * 34 * 136]; // [row(4)][col(34)][ci 128 pad->136]
    __shared__ float sc[8][64];
    __shared__ float bia[9][128];

    const int t  = threadIdx.x;
    const int bx = blockIdx.x;
    const int wt = bx % 3;
    const int h2 = (bx / 3) % 48;
    const int b  = bx / 144;
    const int h0 = h2 * 2, w0 = wt * 32;

    // ---- stage x patch (4 rows x 34 cols x 128 ci), fp32 -> bf16, transposed
    const float* xb = x + b * 128 * 9216;
    for (int i = t; i < 17408; i += 256) {
        int ci  = i / 136;
        int rem = i - ci * 136;
        int row = rem / 34;
        int col = rem - row * 34;
        int hh = h0 - 1 + row;
        int ww = w0 - 1 + col;
        float v = 0.0f;
        if (hh >= 0 && hh < 96 && ww >= 0 && ww < 96)
            v = xb[ci * 9216 + hh * 96 + ww];
        xs[(row * 34 + col) * 136 + ci] = f2bf(v);
    }
    for (int i = t; i < 512; i += 256) {
        int e = i >> 6, p = i & 63;
        sc[e][p] = scores[(b * 8 + e) * 9216 + (h0 + (p >> 5)) * 96 + (w0 + (p & 31))];
    }
    for (int i = t; i < 1152; i += 256) {
        int e = i >> 7, co = i & 127;
        bia[e][co] = (e < 8) ? eb[(e << 7) + co] : sb[co];
    }
    __syncthreads();

    const int wv = t >> 6;
    const int l  = t & 63;
    const int lm = l & 15;   // A: co within frag / B+D: pixel col
    const int lq = l >> 4;   // k-subgroup (A/B); row-group (D)

    // routing weights for this lane's 4 pixel-groups, all experts (registers)
    float sreg[8][4];
    #pragma unroll
    for (int e = 0; e < 8; e++)
        #pragma unroll
        for (int j = 0; j < 4; j++)
            sreg[e][j] = sc[e][j * 16 + lm];

    f32x4 acc[2][4];
    #pragma unroll
    for (int i2 = 0; i2 < 2; i2++)
        #pragma unroll
        for (int j = 0; j < 4; j++)
            acc[i2][j] = (f32x4){0.f, 0.f, 0.f, 0.f};

    const int bBase = lm * 136 + lq * 8;
    // lane's A base within one (e,tap) 128x128 tile (shorts)
    const unsigned short* paw = pw + (wv * 32 + lm) * 128 + lq * 8;

    for (int tap = 0; tap < 9; tap++) {
        const int kh = tap / 3;
        const int kw = tap - kh * 3;
        const int x0 = kh * 4624 + kw * 136 + bBase;     // 4624 = 34*136

        short8 bfr[4][4];                                 // [kc][j]
        #pragma unroll
        for (int kc = 0; kc < 4; kc++)
            #pragma unroll
            for (int j = 0; j < 4; j++)
                bfr[kc][j] = *reinterpret_cast<const short8*>(
                    &xs[x0 + (j >> 1) * 4624 + (j & 1) * 2176 + kc * 32]);

        const unsigned short* pt = paw + tap * 16384;
        #pragma unroll
        for (int e = 0; e < 9; e++) {
            const unsigned short* pe = pt + e * 147456;   // 9*16384
            short8 a0[4], a1[4];
            #pragma unroll
            for (int kc = 0; kc < 4; kc++) {
                a0[kc] = *reinterpret_cast<const short8*>(pe + kc * 32);
                a1[kc] = *reinterpret_cast<const short8*>(pe + 2048 + kc * 32);
            }
            f32x4 accE[2][4];
            #pragma unroll
            for (int i2 = 0; i2 < 2; i2++)
                #pragma unroll
                for (int j = 0; j < 4; j++)
                    accE[i2][j] = (f32x4){0.f, 0.f, 0.f, 0.f};
            #pragma unroll
            for (int kc = 0; kc < 4; kc++) {
                #pragma unroll
                for (int j = 0; j < 4; j++) {
                    accE[0][j] = __builtin_amdgcn_mfma_f32_16x16x32_bf16(a0[kc], bfr[kc][j], accE[0][j], 0, 0, 0);
                    accE[1][j] = __builtin_amdgcn_mfma_f32_16x16x32_bf16(a1[kc], bfr[kc][j], accE[1][j], 0, 0, 0);
                }
            }
            #pragma unroll
            for (int j = 0; j < 4; j++) {
                const float s = (e < 8) ? sreg[e][j] : 1.0f;
                #pragma unroll
                for (int i2 = 0; i2 < 2; i2++)
                    #pragma unroll
                    for (int rr = 0; rr < 4; rr++)
                        acc[i2][j][rr] += s * accE[i2][j][rr];
            }
        }
    }

    // ---- epilogue: bias fold + store (D: col=lm -> pixel, row=lq*4+rr -> co)
    float* ob = out + b * 128 * 9216;
    #pragma unroll
    for (int i2 = 0; i2 < 2; i2++)
        #pragma unroll
        for (int rr = 0; rr < 4; rr++) {
            const int co = wv * 32 + i2 * 16 + lq * 4 + rr;
            float bb[9];
            #pragma unroll
            for (int e = 0; e < 9; e++) bb[e] = bia[e][co];
            #pragma unroll
            for (int j = 0; j < 4; j++) {
                float bsum = bb[8];
                #pragma unroll
                for (int e = 0; e < 8; e++) bsum += sreg[e][j] * bb[e];
                const int hh = h0 + (j >> 1);
                const int ww = w0 + (j & 1) * 16 + lm;
                ob[co * 9216 + hh * 96 + ww] = acc[i2][j][rr] + bsum;
            }
        }
}

// ---------------------------------------------------------------------------
extern "C" void kernel_launch(void* const* d_in, const int* in_sizes, int n_in,
                              void* d_out, int out_size, void* d_ws, size_t ws_size,
                              hipStream_t stream) {
    const float* x  = (const float*)d_in[0];
    const float* gw = (const float*)d_in[1];
    const float* gb = (const float*)d_in[2];
    const float* ew = (const float*)d_in[3];
    const float* eb = (const float*)d_in[4];
    const float* sw = (const float*)d_in[5];
    const float* sb = (const float*)d_in[6];
    float* out = (float*)d_out;

    unsigned short* pw = (unsigned short*)d_ws;                  // 2,654,208 B
    float* scores = (float*)((char*)d_ws + 2654208);             // 1,179,648 B

    prep_kernel<<<144, 256, 0, stream>>>(ew, sw, pw);
    gate_kernel<<<1152, 256, 0, stream>>>(x, gw, gb, scores);
    moe_main_kernel<<<576, 256, 0, stream>>>(x, pw, scores, eb, sb, out);
}

// Round 4
// 911.326 us; speedup vs baseline: 2.2631x; 2.2631x over previous
//
#include <hip/hip_runtime.h>
#include <hip/hip_bf16.h>
#include <math.h>

// Problem constants
// x:(4,128,96,96) gate_w:(8,128,3,3) gate_bias:(8) expert_w:(8,128,128,3,3)
// expert_b:(8,128) shared_w:(128,128,3,3) shared_b:(128)  -> out:(4,128,96,96)

typedef __attribute__((ext_vector_type(8))) short short8;
typedef __attribute__((ext_vector_type(4))) float f32x4;

static __device__ __forceinline__ unsigned short f2bf(float f) {
    unsigned int u = __float_as_uint(f);
    unsigned int r = (u + 0x7FFFu + ((u >> 16) & 1u)) >> 16;
    return (unsigned short)r;
}

// ---------------------------------------------------------------------------
// Prep: ew (8,128,128,3,3) + sw (128,128,3,3) -> bf16
// pw[e(9)][tap(9)][co(128)][ci(128)], LDS transpose for coalesced r/w.
// ---------------------------------------------------------------------------
__global__ __launch_bounds__(256) void prep_kernel(
    const float* __restrict__ ew, const float* __restrict__ sw,
    unsigned short* __restrict__ pw)
{
    __shared__ float buf[8][1152];
    const int t = threadIdx.x;
    const int P = blockIdx.x * 8;         // pair = e*128+co; e==8 -> shared
    for (int i = t; i < 9216; i += 256) {
        int pi   = i / 1152;
        int elem = i - pi * 1152;          // ci*9 + tap
        int pair = P + pi;
        int e  = pair >> 7;
        int co = pair & 127;
        float v = (e < 8) ? ew[(e * 128 + co) * 1152 + elem]
                          : sw[co * 1152 + elem];
        buf[pi][elem] = v;
    }
    __syncthreads();
    for (int o = t; o < 9216; o += 256) {
        int pi  = o / 1152;
        int r   = o - pi * 1152;
        int tap = r >> 7;
        int ci  = r & 127;
        int pair = P + pi;
        int e  = pair >> 7;
        int co = pair & 127;
        pw[((e * 9 + tap) * 128 + co) * 128 + ci] = f2bf(buf[pi][ci * 9 + tap]);
    }
}

// ---------------------------------------------------------------------------
// Gate: fp32 conv -> sigmoid -> top2 -> softmax -> dense score_full.
// Block = 256 thr: 8 ci-groups (16 ci) x 32 pixels. Grid = 1152 blocks.
// ---------------------------------------------------------------------------
__global__ __launch_bounds__(256) void gate_kernel(
    const float* __restrict__ x, const float* __restrict__ gw,
    const float* __restrict__ gb, float* __restrict__ scores)
{
    __shared__ float gws[9216];          // [ci][tap][e] — wave-uniform reads
    __shared__ float red[8][32][8];

    const int t = threadIdx.x;
    for (int i = t; i < 9216; i += 256) {
        int ci  = i / 72;
        int r   = i - ci * 72;
        int tap = r >> 3;
        int e   = r & 7;
        gws[i] = gw[(e * 128 + ci) * 9 + tap];
    }
    __syncthreads();

    const int g  = t >> 5;
    const int p  = t & 31;
    const int bx = blockIdx.x;
    const int wt = bx % 3;
    const int h  = (bx / 3) % 96;
    const int b  = bx / 288;
    const int w  = wt * 32 + p;

    int off[9]; float msk[9];
    #pragma unroll
    for (int kh = 0; kh < 3; kh++) {
        #pragma unroll
        for (int kw = 0; kw < 3; kw++) {
            int hh = h + kh - 1, ww = w + kw - 1;
            bool valid = (hh >= 0 && hh < 96 && ww >= 0 && ww < 96);
            int hc = min(max(hh, 0), 95), wc = min(max(ww, 0), 95);
            off[kh * 3 + kw] = hc * 96 + wc;
            msk[kh * 3 + kw] = valid ? 1.0f : 0.0f;
        }
    }

    const float* xb = x + (b * 128 + g * 16) * 9216;
    float acc[8] = {0.f,0.f,0.f,0.f,0.f,0.f,0.f,0.f};
    #pragma unroll 2
    for (int ci = 0; ci < 16; ci++) {
        const float* xc = xb + ci * 9216;
        const float* wr = &gws[(g * 16 + ci) * 72];
        float xv[9];
        #pragma unroll
        for (int tap = 0; tap < 9; tap++) xv[tap] = xc[off[tap]] * msk[tap];
        #pragma unroll
        for (int tap = 0; tap < 9; tap++) {
            #pragma unroll
            for (int e = 0; e < 8; e++) acc[e] += xv[tap] * wr[tap * 8 + e];
        }
    }

    #pragma unroll
    for (int e = 0; e < 8; e++) red[g][p][e] = acc[e];
    __syncthreads();

    if (t < 32) {
        float s[8], bs[8];
        #pragma unroll
        for (int e = 0; e < 8; e++) {
            float v = 0.f;
            #pragma unroll
            for (int gg = 0; gg < 8; gg++) v += red[gg][t][e];
            s[e]  = 1.0f / (1.0f + expf(-v));
            bs[e] = s[e] + gb[e];
        }
        int i1 = 0; float b1 = bs[0]; float w1 = s[0];
        #pragma unroll
        for (int e = 1; e < 8; e++)
            if (bs[e] > b1) { b1 = bs[e]; i1 = e; w1 = s[e]; }
        int i2 = -1; float b2 = -1e30f; float w2 = 0.f;
        #pragma unroll
        for (int e = 0; e < 8; e++)
            if (e != i1 && bs[e] > b2) { b2 = bs[e]; i2 = e; w2 = s[e]; }

        float mx = fmaxf(w1, w2);
        float e1 = expf(w1 - mx), e2 = expf(w2 - mx);
        float inv = 1.0f / (e1 + e2);
        float p1 = e1 * inv, p2 = e2 * inv;   // ROUTE_SCALE = 1

        int base = b * 8 * 9216 + h * 96 + wt * 32 + t;
        #pragma unroll
        for (int e = 0; e < 8; e++) {
            float v = (e == i1) ? p1 : ((e == i2) ? p2 : 0.0f);
            scores[base + e * 9216] = v;
        }
    }
}

// ---------------------------------------------------------------------------
// Main v3: tap-outer / i2-outer / expert-inner.
// B-frags in registers (reused across i2 and 9 experts), A direct global->VGPR
// (L2-resident weights), scale folded per (e,tap,i2) partial; NO K-loop barriers.
// Register budget: bfr 64 + acc 32 + accE 16 + a 16 + sreg 32 ~= 160+addr.
// ---------------------------------------------------------------------------
__global__ __launch_bounds__(256, 2) void moe_main_kernel(
    const float* __restrict__ x, const unsigned short* __restrict__ pw,
    const float* __restrict__ scores, const float* __restrict__ eb,
    const float* __restrict__ sb, float* __restrict__ out)
{
    __shared__ unsigned short xs[4 * 34 * 136]; // [row(4)][col(34)][ci 128 pad->136]
    __shared__ float sc[8][64];
    __shared__ float bia[9][128];

    const int t  = threadIdx.x;
    const int bx = blockIdx.x;
    const int wt = bx % 3;
    const int h2 = (bx / 3) % 48;
    const int b  = bx / 144;
    const int h0 = h2 * 2, w0 = wt * 32;

    // ---- stage x patch (4 rows x 34 cols x 128 ci), fp32 -> bf16, transposed
    const float* xb = x + b * 128 * 9216;
    for (int i = t; i < 17408; i += 256) {
        int ci  = i / 136;
        int rem = i - ci * 136;
        int row = rem / 34;
        int col = rem - row * 34;
        int hh = h0 - 1 + row;
        int ww = w0 - 1 + col;
        float v = 0.0f;
        if (hh >= 0 && hh < 96 && ww >= 0 && ww < 96)
            v = xb[ci * 9216 + hh * 96 + ww];
        xs[(row * 34 + col) * 136 + ci] = f2bf(v);
    }
    for (int i = t; i < 512; i += 256) {
        int e = i >> 6, p = i & 63;
        sc[e][p] = scores[(b * 8 + e) * 9216 + (h0 + (p >> 5)) * 96 + (w0 + (p & 31))];
    }
    for (int i = t; i < 1152; i += 256) {
        int e = i >> 7, co = i & 127;
        bia[e][co] = (e < 8) ? eb[(e << 7) + co] : sb[co];
    }
    __syncthreads();

    const int wv = t >> 6;
    const int l  = t & 63;
    const int lm = l & 15;   // A: co within frag / B+D: pixel col
    const int lq = l >> 4;   // k-subgroup (A/B); row-group (D)

    float sreg[8][4];
    #pragma unroll
    for (int e = 0; e < 8; e++)
        #pragma unroll
        for (int j = 0; j < 4; j++)
            sreg[e][j] = sc[e][j * 16 + lm];

    f32x4 acc[2][4];
    #pragma unroll
    for (int i2 = 0; i2 < 2; i2++)
        #pragma unroll
        for (int j = 0; j < 4; j++)
            acc[i2][j] = (f32x4){0.f, 0.f, 0.f, 0.f};

    const int bBase = lm * 136 + lq * 8;
    // lane A base within one (e,tap) 128x128 tile: co = wv*32 + i2*16 + lm
    const unsigned short* paw = pw + (wv * 32 + lm) * 128 + lq * 8;

    for (int tap = 0; tap < 9; tap++) {
        const int kh = tap / 3;
        const int kw = tap - kh * 3;
        const int x0 = kh * 4624 + kw * 136 + bBase;     // 4624 = 34*136

        short8 bfr[4][4];                                 // [kc][j]
        #pragma unroll
        for (int kc = 0; kc < 4; kc++)
            #pragma unroll
            for (int j = 0; j < 4; j++)
                bfr[kc][j] = *reinterpret_cast<const short8*>(
                    &xs[x0 + (j >> 1) * 4624 + (j & 1) * 2176 + kc * 32]);

        const unsigned short* pt = paw + tap * 16384;
        #pragma unroll
        for (int i2 = 0; i2 < 2; i2++) {
            const unsigned short* pti = pt + i2 * 2048;   // 16 co rows
            #pragma unroll
            for (int e = 0; e < 9; e++) {
                const unsigned short* pe = pti + e * 147456;   // 9*16384
                short8 a[4];
                #pragma unroll
                for (int kc = 0; kc < 4; kc++)
                    a[kc] = *reinterpret_cast<const short8*>(pe + kc * 32);
                f32x4 accE[4];
                #pragma unroll
                for (int j = 0; j < 4; j++)
                    accE[j] = (f32x4){0.f, 0.f, 0.f, 0.f};
                #pragma unroll
                for (int kc = 0; kc < 4; kc++)
                    #pragma unroll
                    for (int j = 0; j < 4; j++)
                        accE[j] = __builtin_amdgcn_mfma_f32_16x16x32_bf16(a[kc], bfr[kc][j], accE[j], 0, 0, 0);
                #pragma unroll
                for (int j = 0; j < 4; j++) {
                    const float s = (e < 8) ? sreg[e][j] : 1.0f;
                    #pragma unroll
                    for (int rr = 0; rr < 4; rr++)
                        acc[i2][j][rr] += s * accE[j][rr];
                }
            }
        }
    }

    // ---- epilogue: bias fold + store (D: col=lm -> pixel, row=lq*4+rr -> co)
    float* ob = out + b * 128 * 9216;
    #pragma unroll
    for (int i2 = 0; i2 < 2; i2++)
        #pragma unroll
        for (int rr = 0; rr < 4; rr++) {
            const int co = wv * 32 + i2 * 16 + lq * 4 + rr;
            float bb[9];
            #pragma unroll
            for (int e = 0; e < 9; e++) bb[e] = bia[e][co];
            #pragma unroll
            for (int j = 0; j < 4; j++) {
                float bsum = bb[8];
                #pragma unroll
                for (int e = 0; e < 8; e++) bsum += sreg[e][j] * bb[e];
                const int hh = h0 + (j >> 1);
                const int ww = w0 + (j & 1) * 16 + lm;
                ob[co * 9216 + hh * 96 + ww] = acc[i2][j][rr] + bsum;
            }
        }
}

// ---------------------------------------------------------------------------
extern "C" void kernel_launch(void* const* d_in, const int* in_sizes, int n_in,
                              void* d_out, int out_size, void* d_ws, size_t ws_size,
                              hipStream_t stream) {
    const float* x  = (const float*)d_in[0];
    const float* gw = (const float*)d_in[1];
    const float* gb = (const float*)d_in[2];
    const float* ew = (const float*)d_in[3];
    const float* eb = (const float*)d_in[4];
    const float* sw = (const float*)d_in[5];
    const float* sb = (const float*)d_in[6];
    float* out = (float*)d_out;

    unsigned short* pw = (unsigned short*)d_ws;                  // 2,654,208 B
    float* scores = (float*)((char*)d_ws + 2654208);             // 1,179,648 B

    prep_kernel<<<144, 256, 0, stream>>>(ew, sw, pw);
    gate_kernel<<<1152, 256, 0, stream>>>(x, gw, gb, scores);
    moe_main_kernel<<<576, 256, 0, stream>>>(x, pw, scores, eb, sb, out);
}

// Round 5
// 370.989 us; speedup vs baseline: 5.5591x; 2.4565x over previous
//
#include <hip/hip_runtime.h>
#include <hip/hip_bf16.h>
#include <math.h>

// Problem constants
// x:(4,128,96,96) gate_w:(8,128,3,3) gate_bias:(8) expert_w:(8,128,128,3,3)
// expert_b:(8,128) shared_w:(128,128,3,3) shared_b:(128)  -> out:(4,128,96,96)

typedef __attribute__((ext_vector_type(8))) short short8;
typedef __attribute__((ext_vector_type(4))) float f32x4;

static __device__ __forceinline__ unsigned short f2bf(float f) {
    unsigned int u = __float_as_uint(f);
    unsigned int r = (u + 0x7FFFu + ((u >> 16) & 1u)) >> 16;
    return (unsigned short)r;
}

// ---------------------------------------------------------------------------
// Prep: ew (8,128,128,3,3) + sw (128,128,3,3) -> bf16
// pw[e(9)][tap(9)][co(128)][ci(128)], LDS transpose for coalesced r/w.
// ---------------------------------------------------------------------------
__global__ __launch_bounds__(256) void prep_kernel(
    const float* __restrict__ ew, const float* __restrict__ sw,
    unsigned short* __restrict__ pw)
{
    __shared__ float buf[8][1152];
    const int t = threadIdx.x;
    const int P = blockIdx.x * 8;         // pair = e*128+co; e==8 -> shared
    for (int i = t; i < 9216; i += 256) {
        int pi   = i / 1152;
        int elem = i - pi * 1152;          // ci*9 + tap
        int pair = P + pi;
        int e  = pair >> 7;
        int co = pair & 127;
        float v = (e < 8) ? ew[(e * 128 + co) * 1152 + elem]
                          : sw[co * 1152 + elem];
        buf[pi][elem] = v;
    }
    __syncthreads();
    for (int o = t; o < 9216; o += 256) {
        int pi  = o / 1152;
        int r   = o - pi * 1152;
        int tap = r >> 7;
        int ci  = r & 127;
        int pair = P + pi;
        int e  = pair >> 7;
        int co = pair & 127;
        pw[((e * 9 + tap) * 128 + co) * 128 + ci] = f2bf(buf[pi][ci * 9 + tap]);
    }
}

// ---------------------------------------------------------------------------
// Gate: fp32 conv -> sigmoid -> top2 -> softmax -> dense score_full.
// Block = 256 thr: 8 ci-groups (16 ci) x 32 pixels. Grid = 1152 blocks.
// ---------------------------------------------------------------------------
__global__ __launch_bounds__(256) void gate_kernel(
    const float* __restrict__ x, const float* __restrict__ gw,
    const float* __restrict__ gb, float* __restrict__ scores)
{
    __shared__ float gws[9216];          // [ci][tap][e] — wave-uniform reads
    __shared__ float red[8][32][8];

    const int t = threadIdx.x;
    for (int i = t; i < 9216; i += 256) {
        int ci  = i / 72;
        int r   = i - ci * 72;
        int tap = r >> 3;
        int e   = r & 7;
        gws[i] = gw[(e * 128 + ci) * 9 + tap];
    }
    __syncthreads();

    const int g  = t >> 5;
    const int p  = t & 31;
    const int bx = blockIdx.x;
    const int wt = bx % 3;
    const int h  = (bx / 3) % 96;
    const int b  = bx / 288;
    const int w  = wt * 32 + p;

    int off[9]; float msk[9];
    #pragma unroll
    for (int kh = 0; kh < 3; kh++) {
        #pragma unroll
        for (int kw = 0; kw < 3; kw++) {
            int hh = h + kh - 1, ww = w + kw - 1;
            bool valid = (hh >= 0 && hh < 96 && ww >= 0 && ww < 96);
            int hc = min(max(hh, 0), 95), wc = min(max(ww, 0), 95);
            off[kh * 3 + kw] = hc * 96 + wc;
            msk[kh * 3 + kw] = valid ? 1.0f : 0.0f;
        }
    }

    const float* xb = x + (b * 128 + g * 16) * 9216;
    float acc[8] = {0.f,0.f,0.f,0.f,0.f,0.f,0.f,0.f};
    #pragma unroll 2
    for (int ci = 0; ci < 16; ci++) {
        const float* xc = xb + ci * 9216;
        const float* wr = &gws[(g * 16 + ci) * 72];
        float xv[9];
        #pragma unroll
        for (int tap = 0; tap < 9; tap++) xv[tap] = xc[off[tap]] * msk[tap];
        #pragma unroll
        for (int tap = 0; tap < 9; tap++) {
            #pragma unroll
            for (int e = 0; e < 8; e++) acc[e] += xv[tap] * wr[tap * 8 + e];
        }
    }

    #pragma unroll
    for (int e = 0; e < 8; e++) red[g][p][e] = acc[e];
    __syncthreads();

    if (t < 32) {
        float s[8], bs[8];
        #pragma unroll
        for (int e = 0; e < 8; e++) {
            float v = 0.f;
            #pragma unroll
            for (int gg = 0; gg < 8; gg++) v += red[gg][t][e];
            s[e]  = 1.0f / (1.0f + expf(-v));
            bs[e] = s[e] + gb[e];
        }
        int i1 = 0; float b1 = bs[0]; float w1 = s[0];
        #pragma unroll
        for (int e = 1; e < 8; e++)
            if (bs[e] > b1) { b1 = bs[e]; i1 = e; w1 = s[e]; }
        int i2 = -1; float b2 = -1e30f; float w2 = 0.f;
        #pragma unroll
        for (int e = 0; e < 8; e++)
            if (e != i1 && bs[e] > b2) { b2 = bs[e]; i2 = e; w2 = s[e]; }

        float mx = fmaxf(w1, w2);
        float e1 = expf(w1 - mx), e2 = expf(w2 - mx);
        float inv = 1.0f / (e1 + e2);
        float p1 = e1 * inv, p2 = e2 * inv;   // ROUTE_SCALE = 1

        int base = b * 8 * 9216 + h * 96 + wt * 32 + t;
        #pragma unroll
        for (int e = 0; e < 8; e++) {
            float v = (e == i1) ? p1 : ((e == i2) ? p2 : 0.0f);
            scores[base + e * 9216] = v;
        }
    }
}

// ---------------------------------------------------------------------------
// Main v4: tap-outer / expert-inner, register-disciplined.
// #pragma unroll 1 on tap & e loops keeps the live set to ONE iteration:
// bfr 64 + a 16 + acc 32 + s 4 + addr ~10 ≈ 126 arch VGPRs; accE -> AGPR.
// Routing weights read from LDS per expert (broadcast, conflict-free).
// ---------------------------------------------------------------------------
__global__ __launch_bounds__(256, 2) void moe_main_kernel(
    const float* __restrict__ x, const unsigned short* __restrict__ pw,
    const float* __restrict__ scores, const float* __restrict__ eb,
    const float* __restrict__ sb, float* __restrict__ out)
{
    __shared__ unsigned short xs[4 * 34 * 136]; // [row(4)][col(34)][ci 128 pad->136]
    __shared__ float sc[8][64];
    __shared__ float bia[9][128];

    const int t  = threadIdx.x;
    const int bx = blockIdx.x;
    const int wt = bx % 3;
    const int h2 = (bx / 3) % 48;
    const int b  = bx / 144;
    const int h0 = h2 * 2, w0 = wt * 32;

    // ---- stage x patch (4 rows x 34 cols x 128 ci), fp32 -> bf16, transposed
    const float* xb = x + b * 128 * 9216;
    for (int i = t; i < 17408; i += 256) {
        int ci  = i / 136;
        int rem = i - ci * 136;
        int row = rem / 34;
        int col = rem - row * 34;
        int hh = h0 - 1 + row;
        int ww = w0 - 1 + col;
        float v = 0.0f;
        if (hh >= 0 && hh < 96 && ww >= 0 && ww < 96)
            v = xb[ci * 9216 + hh * 96 + ww];
        xs[(row * 34 + col) * 136 + ci] = f2bf(v);
    }
    for (int i = t; i < 512; i += 256) {
        int e = i >> 6, p = i & 63;
        sc[e][p] = scores[(b * 8 + e) * 9216 + (h0 + (p >> 5)) * 96 + (w0 + (p & 31))];
    }
    for (int i = t; i < 1152; i += 256) {
        int e = i >> 7, co = i & 127;
        bia[e][co] = (e < 8) ? eb[(e << 7) + co] : sb[co];
    }
    __syncthreads();

    const int wv = t >> 6;
    const int l  = t & 63;
    const int lm = l & 15;   // A: co within frag / B+D: pixel col
    const int lq = l >> 4;   // k-subgroup (A/B); row-group (D)

    f32x4 acc[2][4];
    #pragma unroll
    for (int i2 = 0; i2 < 2; i2++)
        #pragma unroll
        for (int j = 0; j < 4; j++)
            acc[i2][j] = (f32x4){0.f, 0.f, 0.f, 0.f};

    const int bBase = lm * 136 + lq * 8;
    // lane A base within one (e,tap) 128x128 tile: co = wv*32 + i2*16 + lm
    const unsigned short* paw = pw + (wv * 32 + lm) * 128 + lq * 8;

    #pragma unroll 1
    for (int tap = 0; tap < 9; tap++) {
        const int kh = tap / 3;
        const int kw = tap - kh * 3;
        const int x0 = kh * 4624 + kw * 136 + bBase;     // 4624 = 34*136

        short8 bfr[4][4];                                 // [kc][j] = 64 VGPR
        #pragma unroll
        for (int kc = 0; kc < 4; kc++)
            #pragma unroll
            for (int j = 0; j < 4; j++)
                bfr[kc][j] = *reinterpret_cast<const short8*>(
                    &xs[x0 + (j >> 1) * 4624 + (j & 1) * 2176 + kc * 32]);

        const unsigned short* pt = paw + tap * 16384;
        #pragma unroll 1
        for (int e = 0; e < 9; e++) {
            const unsigned short* pe = pt + e * 147456;   // 9*16384
            float s[4];
            #pragma unroll
            for (int j = 0; j < 4; j++)
                s[j] = (e < 8) ? sc[e][j * 16 + lm] : 1.0f;
            #pragma unroll
            for (int i2 = 0; i2 < 2; i2++) {
                short8 a[4];
                #pragma unroll
                for (int kc = 0; kc < 4; kc++)
                    a[kc] = *reinterpret_cast<const short8*>(pe + i2 * 2048 + kc * 32);
                f32x4 accE[4];
                #pragma unroll
                for (int j = 0; j < 4; j++)
                    accE[j] = (f32x4){0.f, 0.f, 0.f, 0.f};
                #pragma unroll
                for (int kc = 0; kc < 4; kc++)
                    #pragma unroll
                    for (int j = 0; j < 4; j++)
                        accE[j] = __builtin_amdgcn_mfma_f32_16x16x32_bf16(a[kc], bfr[kc][j], accE[j], 0, 0, 0);
                #pragma unroll
                for (int j = 0; j < 4; j++)
                    #pragma unroll
                    for (int rr = 0; rr < 4; rr++)
                        acc[i2][j][rr] += s[j] * accE[j][rr];
            }
        }
    }

    // ---- epilogue: bias fold + store (D: col=lm -> pixel, row=lq*4+rr -> co)
    float* ob = out + b * 128 * 9216;
    #pragma unroll
    for (int i2 = 0; i2 < 2; i2++)
        #pragma unroll
        for (int rr = 0; rr < 4; rr++) {
            const int co = wv * 32 + i2 * 16 + lq * 4 + rr;
            #pragma unroll
            for (int j = 0; j < 4; j++) {
                float bsum = bia[8][co];
                #pragma unroll
                for (int e = 0; e < 8; e++)
                    bsum += sc[e][j * 16 + lm] * bia[e][co];
                const int hh = h0 + (j >> 1);
                const int ww = w0 + (j & 1) * 16 + lm;
                ob[co * 9216 + hh * 96 + ww] = acc[i2][j][rr] + bsum;
            }
        }
}

// ---------------------------------------------------------------------------
extern "C" void kernel_launch(void* const* d_in, const int* in_sizes, int n_in,
                              void* d_out, int out_size, void* d_ws, size_t ws_size,
                              hipStream_t stream) {
    const float* x  = (const float*)d_in[0];
    const float* gw = (const float*)d_in[1];
    const float* gb = (const float*)d_in[2];
    const float* ew = (const float*)d_in[3];
    const float* eb = (const float*)d_in[4];
    const float* sw = (const float*)d_in[5];
    const float* sb = (const float*)d_in[6];
    float* out = (float*)d_out;

    unsigned short* pw = (unsigned short*)d_ws;                  // 2,654,208 B
    float* scores = (float*)((char*)d_ws + 2654208);             // 1,179,648 B

    prep_kernel<<<144, 256, 0, stream>>>(ew, sw, pw);
    gate_kernel<<<1152, 256, 0, stream>>>(x, gw, gb, scores);
    moe_main_kernel<<<576, 256, 0, stream>>>(x, pw, scores, eb, sb, out);
}